// Round 16
// baseline (385.353 us; speedup 1.0000x reference)
//
#include <hip/hip_runtime.h>

#define NN 100000
#define NE 1600000
#define SH 7
#define NB_BKT 782        // ceil(100000/128)
#define BCAP 3072         // edges per bucket cap (mean 2048, sigma~45: >20 sigma)
#define CSRCAP 3200       // BCAP + 128 self-edges
#define CHUNK 8192

static inline int cdiv(long long a, int b) { return (int)((a + b - 1) / b); }

// ======================= bucketed CSR build (fixed-cap, no hist/scan) ====
// packed u32: (r << 7) | (c & 127)
__global__ void partition_kernel(const int* __restrict__ row, const int* __restrict__ col,
                                 int* __restrict__ bcur,
                                 unsigned int* __restrict__ packed, int E) {
    __shared__ int lh[NB_BKT];
    __shared__ int lbase[NB_BKT];
    for (int i = threadIdx.x; i < NB_BKT; i += 256) lh[i] = 0;
    __syncthreads();
    int base = blockIdx.x * CHUNK;
    int end = min(base + CHUNK, E);
    for (int e = base + threadIdx.x; e < end; e += 256) atomicAdd(&lh[col[e] >> SH], 1);
    __syncthreads();
    for (int i = threadIdx.x; i < NB_BKT; i += 256) {
        int v = lh[i];
        lbase[i] = v ? atomicAdd(&bcur[i], v) : 0;
        lh[i] = 0;
    }
    __syncthreads();
    for (int e = base + threadIdx.x; e < end; e += 256) {
        int c = col[e];
        int r = row[e];
        int b = c >> SH;
        int off = atomicAdd(&lh[b], 1);
        packed[lbase[b] + off] = ((unsigned)r << 7) | (unsigned)(c & 127);
    }
}

// Per-bucket: degree count -> scan -> rowptr/rowend/self/dinv -> LDS placement
// -> per-node sort by source row -> coalesced csr_row writeback.
// Sorted segments give the gathers a quasi-sweep access pattern: the i-th edge
// of every segment sits near row-quantile i/deg, so concurrent blocks access a
// narrow sliding row-window -> temporal reuse of h rows in L2.
__global__ void bucket_nodes_place(const unsigned int* __restrict__ packed,
                                   const int* __restrict__ bcur, int* __restrict__ rowptr,
                                   int* __restrict__ rowend, float* __restrict__ dinv,
                                   int* __restrict__ csr_row, int N) {
    int b = blockIdx.x;
    __shared__ int lcnt[128];
    __shared__ int lbase[128];
    __shared__ int lcur[128];
    __shared__ int seg[CSRCAP];    // 12.8 KB
    __shared__ int wt4[4];
    int t = threadIdx.x;
    if (t < 128) lcnt[t] = 0;
    __syncthreads();
    int s = b * BCAP;
    int e = bcur[b];                 // s + edges_in_bucket
    for (int i = s + t; i < e; i += 256)
        atomicAdd(&lcnt[packed[i] & 127u], 1);
    __syncthreads();
    int node = (b << SH) + t;
    int v = (t < 128 && node < N) ? lcnt[t] + 1 : 0;   // +1 = self-edge slot
    int lane = t & 63, w = t >> 6;
    int incl = v;
#pragma unroll
    for (int off = 1; off < 64; off <<= 1) {
        int u = __shfl_up(incl, off, 64);
        if (lane >= off) incl += u;
    }
    if (lane == 63) wt4[w] = incl;
    __syncthreads();
    int woff = 0;
    for (int i = 0; i < w; i++) woff += wt4[i];
    int excl = woff + incl - v;
    if (t < 128 && node < N) {
        rowptr[node] = b * CSRCAP + excl;
        rowend[node] = b * CSRCAP + excl + v;
        dinv[node] = rsqrtf((float)v);
        lbase[t] = excl;
        seg[excl] = node;            // self edge first in segment
        lcur[t] = excl + 1;
    }
    __syncthreads();
    // place edges into LDS segments
    for (int i = s + t; i < e; i += 256) {
        unsigned p = packed[i];
        int r = (int)(p >> 7);
        int pos = atomicAdd(&lcur[p & 127u], 1);
        seg[pos] = r;
    }
    __syncthreads();
    // per-node insertion sort by source row (self edge stays first)
    if (t < 128 && node < N) {
        int st = lbase[t] + 1;
        int len = lcnt[t];
        for (int i = 1; i < len; i++) {
            int key = seg[st + i];
            int j = i - 1;
            while (j >= 0 && seg[st + j] > key) { seg[st + j + 1] = seg[st + j]; j--; }
            seg[st + j + 1] = key;
        }
    }
    __syncthreads();
    // coalesced writeback
    int nodes_in = min(128, N - (b << SH));
    int tot = (e - s) + nodes_in;
    for (int i = t; i < tot; i += 256)
        csr_row[b * CSRCAP + i] = seg[i];
}

// ======================= x pad copy + bcur init ==========================
__global__ void padx_kernel(const float* __restrict__ x, float* __restrict__ xp,
                            int* __restrict__ bcur, int N) {
    int idx = blockIdx.x * blockDim.x + threadIdx.x;
    if (idx < NB_BKT) bcur[idx] = idx * BCAP;
    if (idx >= N * 32) return;
    int n = idx >> 5;
    int k = idx & 31;
    xp[idx] = (k < 21) ? x[n * 21 + k] : 0.f;
}

// ======================= fused gather + GEMM (L1, L2) ====================
// Bank-check: L1 (JG=8,RJ=4): jg*4 spans banks 0..28 distinct -> conflict-free.
// L2 (JG=8,RJ=8): jg*8 mod 32 -> jg,jg+4 pair = 2-way = free (m136).
template <int LPN, int FIN, int FOUT, int RJ, int OSTRIDE>
__global__ __launch_bounds__(512) void gather_gemm(
    const float4* __restrict__ h, const int* __restrict__ rowptr,
    const int* __restrict__ rowend, const int* __restrict__ csr_row,
    const float* __restrict__ dinv, const float* __restrict__ W,
    const float* __restrict__ b, float* __restrict__ out, int N) {
    constexpr int NT = 512 / LPN;        // nodes per block
    constexpr int FINP = 4 * LPN;        // gathered row width (>= FIN)
    constexpr int XLD = FINP + 1;
    constexpr int JG = FOUT / RJ;        // must satisfy 512/JG == NT
    __shared__ float xs[NT * XLD];
    __shared__ float Ws[FIN * FOUT];
    __shared__ float bs[FOUT];
    const int t = threadIdx.x;

    for (int i = t; i < FIN * FOUT; i += 512) Ws[i] = W[i];
    if (t < FOUT) bs[t] = b[t];

    // ---- gather phase ----
    const int l = t % LPN;
    const int ny = t / LPN;
    const int node = blockIdx.x * NT + ny;
    float4 acc = make_float4(0.f, 0.f, 0.f, 0.f);
    if (node < N) {
        int s = rowptr[node], e = rowend[node];
        float dn = dinv[node];
        int i = s;
        for (; i + 3 < e; i += 4) {
            int r0 = csr_row[i], r1 = csr_row[i + 1], r2 = csr_row[i + 2], r3 = csr_row[i + 3];
            float w0 = dinv[r0] * dn, w1 = dinv[r1] * dn, w2 = dinv[r2] * dn, w3 = dinv[r3] * dn;
            float4 a0 = h[(size_t)r0 * LPN + l];
            float4 a1 = h[(size_t)r1 * LPN + l];
            float4 a2 = h[(size_t)r2 * LPN + l];
            float4 a3 = h[(size_t)r3 * LPN + l];
            acc.x = fmaf(w0, a0.x, acc.x); acc.y = fmaf(w0, a0.y, acc.y);
            acc.z = fmaf(w0, a0.z, acc.z); acc.w = fmaf(w0, a0.w, acc.w);
            acc.x = fmaf(w1, a1.x, acc.x); acc.y = fmaf(w1, a1.y, acc.y);
            acc.z = fmaf(w1, a1.z, acc.z); acc.w = fmaf(w1, a1.w, acc.w);
            acc.x = fmaf(w2, a2.x, acc.x); acc.y = fmaf(w2, a2.y, acc.y);
            acc.z = fmaf(w2, a2.z, acc.z); acc.w = fmaf(w2, a2.w, acc.w);
            acc.x = fmaf(w3, a3.x, acc.x); acc.y = fmaf(w3, a3.y, acc.y);
            acc.z = fmaf(w3, a3.z, acc.z); acc.w = fmaf(w3, a3.w, acc.w);
        }
        for (; i < e; i++) {
            int r0 = csr_row[i];
            float w0 = dinv[r0] * dn;
            float4 a0 = h[(size_t)r0 * LPN + l];
            acc.x = fmaf(w0, a0.x, acc.x); acc.y = fmaf(w0, a0.y, acc.y);
            acc.z = fmaf(w0, a0.z, acc.z); acc.w = fmaf(w0, a0.w, acc.w);
        }
    }
    xs[ny * XLD + 4 * l + 0] = acc.x;
    xs[ny * XLD + 4 * l + 1] = acc.y;
    xs[ny * XLD + 4 * l + 2] = acc.z;
    xs[ny * XLD + 4 * l + 3] = acc.w;
    __syncthreads();

    // ---- GEMM phase ----
    const int jg = t % JG;
    const int ng = t / JG;
    float r[RJ];
#pragma unroll
    for (int jj = 0; jj < RJ; jj++) r[jj] = 0.f;
#pragma unroll 4
    for (int k = 0; k < FIN; k++) {
        float xv = xs[ng * XLD + k];
#pragma unroll
        for (int jj = 0; jj < RJ; jj++)
            r[jj] = fmaf(xv, Ws[k * FOUT + jg * RJ + jj], r[jj]);
    }
    int onode = blockIdx.x * NT + ng;
    if (onode < N) {
        float* orow = out + (size_t)onode * OSTRIDE + jg * RJ;
#pragma unroll
        for (int jj = 0; jj < RJ; jj++) r[jj] = fmaxf(r[jj] + bs[jg * RJ + jj], 0.f);
#pragma unroll
        for (int c = 0; c < RJ / 4; c++)
            *(float4*)&orow[4 * c] = make_float4(r[4 * c], r[4 * c + 1], r[4 * c + 2], r[4 * c + 3]);
    }
}

// ======================= standalone gather (unroll 4 — r10 proven) =======
template <int LPN, bool BIAS, bool STORE21>
__global__ void gather4_kernel(const float4* __restrict__ h, const int* __restrict__ rowptr,
                               const int* __restrict__ rowend, const int* __restrict__ csr_row,
                               const float* __restrict__ dinv, const float* __restrict__ bias,
                               float* __restrict__ outp, int N) {
    int node = blockIdx.x * blockDim.y + threadIdx.y;
    if (node >= N) return;
    int l = threadIdx.x;
    int s = rowptr[node], e = rowend[node];
    float dn = dinv[node];
    float4 acc = make_float4(0.f, 0.f, 0.f, 0.f);
    int i = s;
    for (; i + 3 < e; i += 4) {
        int r0 = csr_row[i], r1 = csr_row[i + 1], r2 = csr_row[i + 2], r3 = csr_row[i + 3];
        float w0 = dinv[r0] * dn, w1 = dinv[r1] * dn, w2 = dinv[r2] * dn, w3 = dinv[r3] * dn;
        float4 a0 = h[(size_t)r0 * LPN + l];
        float4 a1 = h[(size_t)r1 * LPN + l];
        float4 a2 = h[(size_t)r2 * LPN + l];
        float4 a3 = h[(size_t)r3 * LPN + l];
        acc.x = fmaf(w0, a0.x, acc.x); acc.y = fmaf(w0, a0.y, acc.y);
        acc.z = fmaf(w0, a0.z, acc.z); acc.w = fmaf(w0, a0.w, acc.w);
        acc.x = fmaf(w1, a1.x, acc.x); acc.y = fmaf(w1, a1.y, acc.y);
        acc.z = fmaf(w1, a1.z, acc.z); acc.w = fmaf(w1, a1.w, acc.w);
        acc.x = fmaf(w2, a2.x, acc.x); acc.y = fmaf(w2, a2.y, acc.y);
        acc.z = fmaf(w2, a2.z, acc.z); acc.w = fmaf(w2, a2.w, acc.w);
        acc.x = fmaf(w3, a3.x, acc.x); acc.y = fmaf(w3, a3.y, acc.y);
        acc.z = fmaf(w3, a3.z, acc.z); acc.w = fmaf(w3, a3.w, acc.w);
    }
    for (; i < e; i++) {
        int r0 = csr_row[i];
        float w0 = dinv[r0] * dn;
        float4 a0 = h[(size_t)r0 * LPN + l];
        acc.x = fmaf(w0, a0.x, acc.x); acc.y = fmaf(w0, a0.y, acc.y);
        acc.z = fmaf(w0, a0.z, acc.z); acc.w = fmaf(w0, a0.w, acc.w);
    }
    if (STORE21) {
        int j = 4 * l;
        float v[4] = {acc.x, acc.y, acc.z, acc.w};
#pragma unroll
        for (int c = 0; c < 4; c++) {
            int jj = j + c;
            if (jj < 21) outp[(size_t)node * 21 + jj] = v[c] + (BIAS ? bias[jj] : 0.f);
        }
    } else {
        ((float4*)outp)[(size_t)node * LPN + l] = acc;
    }
}

// ======================= fused L3+L4 GEMM (RN=2 proven; h4 stride 24) ====
// RN=3 spills regardless of launch_bounds (r11: 84-cap, r13: 128-cap).
// RN=2 fits at 68 VGPR, ~40us. RN tuning closed.
__global__ __launch_bounds__(256, 3) void gemm_l3l4(
    const float* __restrict__ agg, const float* __restrict__ W3,
    const float* __restrict__ b3, const float* __restrict__ W4,
    float* __restrict__ out, int N) {
    __shared__ float4 W3v[64 * 32];
    __shared__ float4 W4v[16 * 48];
    __shared__ float b3s[128];
    const int t = threadIdx.x;
    const int node0 = blockIdx.x * 64;

    for (int sid = t; sid < 64 * 32; sid += 256) {
        int k = sid >> 5, q = sid & 31;
        int jg = q >> 2, c = q & 3;
        W3v[(k << 5) + (c << 3) + jg] = ((const float4*)W3)[sid];
    }
    for (int cid = t; cid < 16 * 48; cid += 256) {
        int i = cid / 48, rem = cid - i * 48;
        int jq = rem >> 3, jg = rem & 7;
        int k = jg * 16 + i;
        float v0 = (4 * jq + 0 < 21) ? W4[k * 21 + 4 * jq + 0] : 0.f;
        float v1 = (4 * jq + 1 < 21) ? W4[k * 21 + 4 * jq + 1] : 0.f;
        float v2 = (4 * jq + 2 < 21) ? W4[k * 21 + 4 * jq + 2] : 0.f;
        float v3 = (4 * jq + 3 < 21) ? W4[k * 21 + 4 * jq + 3] : 0.f;
        W4v[cid] = make_float4(v0, v1, v2, v3);
    }
    if (t < 128) b3s[t] = b3[t];
    __syncthreads();

    const int jg = t & 7;
    const int ng = t >> 3;
    const int nodeA = node0 + ng;
    const int nodeB = node0 + 32 + ng;
    const float* arowA = agg + (size_t)(nodeA < N ? nodeA : N - 1) * 64;
    const float* arowB = agg + (size_t)(nodeB < N ? nodeB : N - 1) * 64;

    float accA[16], accB[16];
#pragma unroll
    for (int jj = 0; jj < 16; jj++) { accA[jj] = 0.f; accB[jj] = 0.f; }
#pragma unroll 4
    for (int k = 0; k < 64; k++) {
        float xa = arowA[k];
        float xb = arowB[k];
        const float4* wb = &W3v[(k << 5) + jg];
#pragma unroll
        for (int c = 0; c < 4; c++) {
            float4 w = wb[c << 3];
            accA[4 * c + 0] = fmaf(xa, w.x, accA[4 * c + 0]);
            accA[4 * c + 1] = fmaf(xa, w.y, accA[4 * c + 1]);
            accA[4 * c + 2] = fmaf(xa, w.z, accA[4 * c + 2]);
            accA[4 * c + 3] = fmaf(xa, w.w, accA[4 * c + 3]);
            accB[4 * c + 0] = fmaf(xb, w.x, accB[4 * c + 0]);
            accB[4 * c + 1] = fmaf(xb, w.y, accB[4 * c + 1]);
            accB[4 * c + 2] = fmaf(xb, w.z, accB[4 * c + 2]);
            accB[4 * c + 3] = fmaf(xb, w.w, accB[4 * c + 3]);
        }
    }
#pragma unroll
    for (int jj = 0; jj < 16; jj++) {
        float bb = b3s[jg * 16 + jj];
        accA[jj] = fmaxf(accA[jj] + bb, 0.f);
        accB[jj] = fmaxf(accB[jj] + bb, 0.f);
    }

    float pA[24], pB[24];
#pragma unroll
    for (int j = 0; j < 24; j++) { pA[j] = 0.f; pB[j] = 0.f; }
#pragma unroll
    for (int i = 0; i < 16; i++) {
        float ha = accA[i];
        float hb = accB[i];
        const float4* wb = &W4v[i * 48 + jg];
#pragma unroll
        for (int jq = 0; jq < 6; jq++) {
            float4 w = wb[jq << 3];
            pA[4 * jq + 0] = fmaf(ha, w.x, pA[4 * jq + 0]);
            pA[4 * jq + 1] = fmaf(ha, w.y, pA[4 * jq + 1]);
            pA[4 * jq + 2] = fmaf(ha, w.z, pA[4 * jq + 2]);
            pA[4 * jq + 3] = fmaf(ha, w.w, pA[4 * jq + 3]);
            pB[4 * jq + 0] = fmaf(hb, w.x, pB[4 * jq + 0]);
            pB[4 * jq + 1] = fmaf(hb, w.y, pB[4 * jq + 1]);
            pB[4 * jq + 2] = fmaf(hb, w.z, pB[4 * jq + 2]);
            pB[4 * jq + 3] = fmaf(hb, w.w, pB[4 * jq + 3]);
        }
    }
#pragma unroll
    for (int m = 1; m < 8; m <<= 1) {
#pragma unroll
        for (int j = 0; j < 24; j++) {
            pA[j] += __shfl_xor(pA[j], m, 8);
            pB[j] += __shfl_xor(pB[j], m, 8);
        }
    }
    if (nodeA < N) {
        float* orow = out + (size_t)nodeA * 24 + jg * 3;
        orow[0] = pA[jg * 3 + 0];
        orow[1] = pA[jg * 3 + 1];
        orow[2] = pA[jg * 3 + 2];
    }
    if (nodeB < N) {
        float* orow = out + (size_t)nodeB * 24 + jg * 3;
        orow[0] = pB[jg * 3 + 0];
        orow[1] = pB[jg * 3 + 1];
        orow[2] = pB[jg * 3 + 2];
    }
}

// ======================= launch ==========================================
extern "C" void kernel_launch(void* const* d_in, const int* in_sizes, int n_in,
                              void* d_out, int out_size, void* d_ws, size_t ws_size,
                              hipStream_t stream) {
    const float* x  = (const float*)d_in[0];
    const int*   ei = (const int*)d_in[1];
    const float* W1 = (const float*)d_in[2]; const float* b1 = (const float*)d_in[3];
    const float* W2 = (const float*)d_in[4]; const float* b2 = (const float*)d_in[5];
    const float* W3 = (const float*)d_in[6]; const float* b3 = (const float*)d_in[7];
    const float* W4 = (const float*)d_in[8]; const float* b4 = (const float*)d_in[9];
    const int* row = ei;
    const int* col = ei + NE;
    float* out = (float*)d_out;

    // workspace layout (floats)
    float* A      = (float*)d_ws;                  // N x 128
    float* B      = A + (size_t)NN * 128;          // N x 128
    float* dinv   = B + (size_t)NN * 128;          // N
    int*   rowptr = (int*)(dinv + NN);             // N
    int*   rowend = rowptr + NN;                   // N
    int*   csr_row= rowend + NN;                   // NB_BKT * CSRCAP = 2.5M
    int*   bcur   = csr_row + (size_t)NB_BKT * CSRCAP;   // NB_BKT
    // packed u32 (r<<7 | c&127), bucket-strided cap BCAP; aliases A (dead pre-L1)
    unsigned int* packed = (unsigned int*)A;       // NB_BKT * BCAP = 2.4M < N*128

    const int BS = 256;
    const int NCH = cdiv(NE, CHUNK);    // 196

    // ---- padx + bcur init ----
    padx_kernel<<<cdiv((long long)NN * 32, BS), BS, 0, stream>>>(x, B, bcur, NN);
    // ---- fixed-cap bucketed CSR build (2 dispatches) ----
    partition_kernel<<<NCH, 256, 0, stream>>>(row, col, bcur, packed, NE);
    bucket_nodes_place<<<NB_BKT, 256, 0, stream>>>(packed, bcur, rowptr, rowend, dinv, csr_row, NN);

    // ---- L1: fused gather(x32)+gemm 21->32 +b relu : B -> A (stride 32) ----
    gather_gemm<8, 21, 32, 4, 32><<<cdiv(NN, 64), 512, 0, stream>>>(
        (const float4*)B, rowptr, rowend, csr_row, dinv, W1, b1, A, NN);
    // ---- L2: fused gather(h1)+gemm 32->64 +b relu : A -> B (stride 64) ----
    gather_gemm<8, 32, 64, 8, 64><<<cdiv(NN, 64), 512, 0, stream>>>(
        (const float4*)A, rowptr, rowend, csr_row, dinv, W2, b2, B, NN);
    // ---- L3 gather: B -> A (stride 64) ----
    {
        dim3 blk(16, 16);
        gather4_kernel<16, false, false><<<cdiv(NN, 16), blk, 0, stream>>>(
            (const float4*)B, rowptr, rowend, csr_row, dinv, nullptr, A, NN);
    }
    // ---- fused L3+L4 GEMM: A -> B (h4, stride 24) ----
    gemm_l3l4<<<cdiv(NN, 64), 256, 0, stream>>>(A, W3, b3, W4, B, NN);
    // ---- L4 gather + b4: B -> out (stride 21); 96 B/edge rows ----
    {
        dim3 blk(6, 42);
        gather4_kernel<6, true, true><<<cdiv(NN, 42), blk, 0, stream>>>(
            (const float4*)B, rowptr, rowend, csr_row, dinv, b4, out, NN);
    }
}

// Round 17
// 350.921 us; speedup vs baseline: 1.0981x; 1.0981x over previous
//
#include <hip/hip_runtime.h>

#define NN 100000
#define NE 1600000
#define SH 7
#define NB_BKT 782        // ceil(100000/128)
#define BCAP 3072         // edges per bucket cap (mean 2048, sigma~45: >20 sigma)
#define CSRCAP 3200       // BCAP + 128 self-edges
#define CHUNK 8192

static inline int cdiv(long long a, int b) { return (int)((a + b - 1) / b); }

// ======================= bucketed CSR build (fixed-cap, no hist/scan) ====
// packed u32: (r << 7) | (c & 127)
__global__ void partition_kernel(const int* __restrict__ row, const int* __restrict__ col,
                                 int* __restrict__ bcur,
                                 unsigned int* __restrict__ packed, int E) {
    __shared__ int lh[NB_BKT];
    __shared__ int lbase[NB_BKT];
    for (int i = threadIdx.x; i < NB_BKT; i += 256) lh[i] = 0;
    __syncthreads();
    int base = blockIdx.x * CHUNK;
    int end = min(base + CHUNK, E);
    for (int e = base + threadIdx.x; e < end; e += 256) atomicAdd(&lh[col[e] >> SH], 1);
    __syncthreads();
    for (int i = threadIdx.x; i < NB_BKT; i += 256) {
        int v = lh[i];
        lbase[i] = v ? atomicAdd(&bcur[i], v) : 0;
        lh[i] = 0;
    }
    __syncthreads();
    for (int e = base + threadIdx.x; e < end; e += 256) {
        int c = col[e];
        int r = row[e];
        int b = c >> SH;
        int off = atomicAdd(&lh[b], 1);
        packed[lbase[b] + off] = ((unsigned)r << 7) | (unsigned)(c & 127);
    }
}

// Per-bucket: degree count -> scan -> rowptr/rowend/self/dinv -> placement.
// NOTE r16: sorting segments by source row does NOT help (FETCH 195.7->193.1MB
// only; deg~17 over 100k rows leaves ~6000-row gaps between sorted neighbors,
// no temporal window) and the per-node insertion sort costs ~+30us. Unsorted.
__global__ void bucket_nodes_place(const unsigned int* __restrict__ packed,
                                   const int* __restrict__ bcur, int* __restrict__ rowptr,
                                   int* __restrict__ rowend, float* __restrict__ dinv,
                                   int* __restrict__ csr_row, int N) {
    int b = blockIdx.x;
    __shared__ int lcnt[128];
    __shared__ int lcur[128];
    __shared__ int wt4[4];
    int t = threadIdx.x;
    if (t < 128) lcnt[t] = 0;
    __syncthreads();
    int s = b * BCAP;
    int e = bcur[b];                 // s + edges_in_bucket
    for (int i = s + t; i < e; i += 256)
        atomicAdd(&lcnt[packed[i] & 127u], 1);
    __syncthreads();
    int node = (b << SH) + t;
    int v = (t < 128 && node < N) ? lcnt[t] + 1 : 0;   // +1 = self-edge slot
    int lane = t & 63, w = t >> 6;
    int incl = v;
#pragma unroll
    for (int off = 1; off < 64; off <<= 1) {
        int u = __shfl_up(incl, off, 64);
        if (lane >= off) incl += u;
    }
    if (lane == 63) wt4[w] = incl;
    __syncthreads();
    int woff = 0;
    for (int i = 0; i < w; i++) woff += wt4[i];
    int excl = woff + incl - v;
    if (t < 128 && node < N) {
        int start = b * CSRCAP + excl;
        rowptr[node] = start;
        rowend[node] = start + v;
        csr_row[start] = node;       // self edge first in segment
        dinv[node] = rsqrtf((float)v);
        lcur[t] = start + 1;
    }
    __syncthreads();
    for (int i = s + t; i < e; i += 256) {   // packed range is L2-warm
        unsigned p = packed[i];
        int r = (int)(p >> 7);
        int pos = atomicAdd(&lcur[p & 127u], 1);
        csr_row[pos] = r;
    }
}

// ======================= x pad copy + bcur init ==========================
__global__ void padx_kernel(const float* __restrict__ x, float* __restrict__ xp,
                            int* __restrict__ bcur, int N) {
    int idx = blockIdx.x * blockDim.x + threadIdx.x;
    if (idx < NB_BKT) bcur[idx] = idx * BCAP;
    if (idx >= N * 32) return;
    int n = idx >> 5;
    int k = idx & 31;
    xp[idx] = (k < 21) ? x[n * 21 + k] : 0.f;
}

// ======================= fused gather + GEMM (L1, L2) ====================
// Bank-check: L1 (JG=8,RJ=4): jg*4 spans banks 0..28 distinct -> conflict-free.
// L2 (JG=8,RJ=8): jg*8 mod 32 -> jg,jg+4 pair = 2-way = free (m136).
template <int LPN, int FIN, int FOUT, int RJ, int OSTRIDE>
__global__ __launch_bounds__(512) void gather_gemm(
    const float4* __restrict__ h, const int* __restrict__ rowptr,
    const int* __restrict__ rowend, const int* __restrict__ csr_row,
    const float* __restrict__ dinv, const float* __restrict__ W,
    const float* __restrict__ b, float* __restrict__ out, int N) {
    constexpr int NT = 512 / LPN;        // nodes per block
    constexpr int FINP = 4 * LPN;        // gathered row width (>= FIN)
    constexpr int XLD = FINP + 1;
    constexpr int JG = FOUT / RJ;        // must satisfy 512/JG == NT
    __shared__ float xs[NT * XLD];
    __shared__ float Ws[FIN * FOUT];
    __shared__ float bs[FOUT];
    const int t = threadIdx.x;

    for (int i = t; i < FIN * FOUT; i += 512) Ws[i] = W[i];
    if (t < FOUT) bs[t] = b[t];

    // ---- gather phase ----
    const int l = t % LPN;
    const int ny = t / LPN;
    const int node = blockIdx.x * NT + ny;
    float4 acc = make_float4(0.f, 0.f, 0.f, 0.f);
    if (node < N) {
        int s = rowptr[node], e = rowend[node];
        float dn = dinv[node];
        int i = s;
        for (; i + 3 < e; i += 4) {
            int r0 = csr_row[i], r1 = csr_row[i + 1], r2 = csr_row[i + 2], r3 = csr_row[i + 3];
            float w0 = dinv[r0] * dn, w1 = dinv[r1] * dn, w2 = dinv[r2] * dn, w3 = dinv[r3] * dn;
            float4 a0 = h[(size_t)r0 * LPN + l];
            float4 a1 = h[(size_t)r1 * LPN + l];
            float4 a2 = h[(size_t)r2 * LPN + l];
            float4 a3 = h[(size_t)r3 * LPN + l];
            acc.x = fmaf(w0, a0.x, acc.x); acc.y = fmaf(w0, a0.y, acc.y);
            acc.z = fmaf(w0, a0.z, acc.z); acc.w = fmaf(w0, a0.w, acc.w);
            acc.x = fmaf(w1, a1.x, acc.x); acc.y = fmaf(w1, a1.y, acc.y);
            acc.z = fmaf(w1, a1.z, acc.z); acc.w = fmaf(w1, a1.w, acc.w);
            acc.x = fmaf(w2, a2.x, acc.x); acc.y = fmaf(w2, a2.y, acc.y);
            acc.z = fmaf(w2, a2.z, acc.z); acc.w = fmaf(w2, a2.w, acc.w);
            acc.x = fmaf(w3, a3.x, acc.x); acc.y = fmaf(w3, a3.y, acc.y);
            acc.z = fmaf(w3, a3.z, acc.z); acc.w = fmaf(w3, a3.w, acc.w);
        }
        for (; i < e; i++) {
            int r0 = csr_row[i];
            float w0 = dinv[r0] * dn;
            float4 a0 = h[(size_t)r0 * LPN + l];
            acc.x = fmaf(w0, a0.x, acc.x); acc.y = fmaf(w0, a0.y, acc.y);
            acc.z = fmaf(w0, a0.z, acc.z); acc.w = fmaf(w0, a0.w, acc.w);
        }
    }
    xs[ny * XLD + 4 * l + 0] = acc.x;
    xs[ny * XLD + 4 * l + 1] = acc.y;
    xs[ny * XLD + 4 * l + 2] = acc.z;
    xs[ny * XLD + 4 * l + 3] = acc.w;
    __syncthreads();

    // ---- GEMM phase ----
    const int jg = t % JG;
    const int ng = t / JG;
    float r[RJ];
#pragma unroll
    for (int jj = 0; jj < RJ; jj++) r[jj] = 0.f;
#pragma unroll 4
    for (int k = 0; k < FIN; k++) {
        float xv = xs[ng * XLD + k];
#pragma unroll
        for (int jj = 0; jj < RJ; jj++)
            r[jj] = fmaf(xv, Ws[k * FOUT + jg * RJ + jj], r[jj]);
    }
    int onode = blockIdx.x * NT + ng;
    if (onode < N) {
        float* orow = out + (size_t)onode * OSTRIDE + jg * RJ;
#pragma unroll
        for (int jj = 0; jj < RJ; jj++) r[jj] = fmaxf(r[jj] + bs[jg * RJ + jj], 0.f);
#pragma unroll
        for (int c = 0; c < RJ / 4; c++)
            *(float4*)&orow[4 * c] = make_float4(r[4 * c], r[4 * c + 1], r[4 * c + 2], r[4 * c + 3]);
    }
}

// ======================= standalone gather (unroll 4 — r10 proven) =======
template <int LPN, bool BIAS, bool STORE21>
__global__ void gather4_kernel(const float4* __restrict__ h, const int* __restrict__ rowptr,
                               const int* __restrict__ rowend, const int* __restrict__ csr_row,
                               const float* __restrict__ dinv, const float* __restrict__ bias,
                               float* __restrict__ outp, int N) {
    int node = blockIdx.x * blockDim.y + threadIdx.y;
    if (node >= N) return;
    int l = threadIdx.x;
    int s = rowptr[node], e = rowend[node];
    float dn = dinv[node];
    float4 acc = make_float4(0.f, 0.f, 0.f, 0.f);
    int i = s;
    for (; i + 3 < e; i += 4) {
        int r0 = csr_row[i], r1 = csr_row[i + 1], r2 = csr_row[i + 2], r3 = csr_row[i + 3];
        float w0 = dinv[r0] * dn, w1 = dinv[r1] * dn, w2 = dinv[r2] * dn, w3 = dinv[r3] * dn;
        float4 a0 = h[(size_t)r0 * LPN + l];
        float4 a1 = h[(size_t)r1 * LPN + l];
        float4 a2 = h[(size_t)r2 * LPN + l];
        float4 a3 = h[(size_t)r3 * LPN + l];
        acc.x = fmaf(w0, a0.x, acc.x); acc.y = fmaf(w0, a0.y, acc.y);
        acc.z = fmaf(w0, a0.z, acc.z); acc.w = fmaf(w0, a0.w, acc.w);
        acc.x = fmaf(w1, a1.x, acc.x); acc.y = fmaf(w1, a1.y, acc.y);
        acc.z = fmaf(w1, a1.z, acc.z); acc.w = fmaf(w1, a1.w, acc.w);
        acc.x = fmaf(w2, a2.x, acc.x); acc.y = fmaf(w2, a2.y, acc.y);
        acc.z = fmaf(w2, a2.z, acc.z); acc.w = fmaf(w2, a2.w, acc.w);
        acc.x = fmaf(w3, a3.x, acc.x); acc.y = fmaf(w3, a3.y, acc.y);
        acc.z = fmaf(w3, a3.z, acc.z); acc.w = fmaf(w3, a3.w, acc.w);
    }
    for (; i < e; i++) {
        int r0 = csr_row[i];
        float w0 = dinv[r0] * dn;
        float4 a0 = h[(size_t)r0 * LPN + l];
        acc.x = fmaf(w0, a0.x, acc.x); acc.y = fmaf(w0, a0.y, acc.y);
        acc.z = fmaf(w0, a0.z, acc.z); acc.w = fmaf(w0, a0.w, acc.w);
    }
    if (STORE21) {
        int j = 4 * l;
        float v[4] = {acc.x, acc.y, acc.z, acc.w};
#pragma unroll
        for (int c = 0; c < 4; c++) {
            int jj = j + c;
            if (jj < 21) outp[(size_t)node * 21 + jj] = v[c] + (BIAS ? bias[jj] : 0.f);
        }
    } else {
        ((float4*)outp)[(size_t)node * LPN + l] = acc;
    }
}

// ======================= fused L3+L4 GEMM (RN=2 proven; h4 stride 24) ====
// RN=3 spills regardless of launch_bounds (r11: 84-cap, r13: 128-cap).
// RN=2 fits at 68 VGPR, ~40us. RN tuning closed.
__global__ __launch_bounds__(256, 3) void gemm_l3l4(
    const float* __restrict__ agg, const float* __restrict__ W3,
    const float* __restrict__ b3, const float* __restrict__ W4,
    float* __restrict__ out, int N) {
    __shared__ float4 W3v[64 * 32];
    __shared__ float4 W4v[16 * 48];
    __shared__ float b3s[128];
    const int t = threadIdx.x;
    const int node0 = blockIdx.x * 64;

    for (int sid = t; sid < 64 * 32; sid += 256) {
        int k = sid >> 5, q = sid & 31;
        int jg = q >> 2, c = q & 3;
        W3v[(k << 5) + (c << 3) + jg] = ((const float4*)W3)[sid];
    }
    for (int cid = t; cid < 16 * 48; cid += 256) {
        int i = cid / 48, rem = cid - i * 48;
        int jq = rem >> 3, jg = rem & 7;
        int k = jg * 16 + i;
        float v0 = (4 * jq + 0 < 21) ? W4[k * 21 + 4 * jq + 0] : 0.f;
        float v1 = (4 * jq + 1 < 21) ? W4[k * 21 + 4 * jq + 1] : 0.f;
        float v2 = (4 * jq + 2 < 21) ? W4[k * 21 + 4 * jq + 2] : 0.f;
        float v3 = (4 * jq + 3 < 21) ? W4[k * 21 + 4 * jq + 3] : 0.f;
        W4v[cid] = make_float4(v0, v1, v2, v3);
    }
    if (t < 128) b3s[t] = b3[t];
    __syncthreads();

    const int jg = t & 7;
    const int ng = t >> 3;
    const int nodeA = node0 + ng;
    const int nodeB = node0 + 32 + ng;
    const float* arowA = agg + (size_t)(nodeA < N ? nodeA : N - 1) * 64;
    const float* arowB = agg + (size_t)(nodeB < N ? nodeB : N - 1) * 64;

    float accA[16], accB[16];
#pragma unroll
    for (int jj = 0; jj < 16; jj++) { accA[jj] = 0.f; accB[jj] = 0.f; }
#pragma unroll 4
    for (int k = 0; k < 64; k++) {
        float xa = arowA[k];
        float xb = arowB[k];
        const float4* wb = &W3v[(k << 5) + jg];
#pragma unroll
        for (int c = 0; c < 4; c++) {
            float4 w = wb[c << 3];
            accA[4 * c + 0] = fmaf(xa, w.x, accA[4 * c + 0]);
            accA[4 * c + 1] = fmaf(xa, w.y, accA[4 * c + 1]);
            accA[4 * c + 2] = fmaf(xa, w.z, accA[4 * c + 2]);
            accA[4 * c + 3] = fmaf(xa, w.w, accA[4 * c + 3]);
            accB[4 * c + 0] = fmaf(xb, w.x, accB[4 * c + 0]);
            accB[4 * c + 1] = fmaf(xb, w.y, accB[4 * c + 1]);
            accB[4 * c + 2] = fmaf(xb, w.z, accB[4 * c + 2]);
            accB[4 * c + 3] = fmaf(xb, w.w, accB[4 * c + 3]);
        }
    }
#pragma unroll
    for (int jj = 0; jj < 16; jj++) {
        float bb = b3s[jg * 16 + jj];
        accA[jj] = fmaxf(accA[jj] + bb, 0.f);
        accB[jj] = fmaxf(accB[jj] + bb, 0.f);
    }

    float pA[24], pB[24];
#pragma unroll
    for (int j = 0; j < 24; j++) { pA[j] = 0.f; pB[j] = 0.f; }
#pragma unroll
    for (int i = 0; i < 16; i++) {
        float ha = accA[i];
        float hb = accB[i];
        const float4* wb = &W4v[i * 48 + jg];
#pragma unroll
        for (int jq = 0; jq < 6; jq++) {
            float4 w = wb[jq << 3];
            pA[4 * jq + 0] = fmaf(ha, w.x, pA[4 * jq + 0]);
            pA[4 * jq + 1] = fmaf(ha, w.y, pA[4 * jq + 1]);
            pA[4 * jq + 2] = fmaf(ha, w.z, pA[4 * jq + 2]);
            pA[4 * jq + 3] = fmaf(ha, w.w, pA[4 * jq + 3]);
            pB[4 * jq + 0] = fmaf(hb, w.x, pB[4 * jq + 0]);
            pB[4 * jq + 1] = fmaf(hb, w.y, pB[4 * jq + 1]);
            pB[4 * jq + 2] = fmaf(hb, w.z, pB[4 * jq + 2]);
            pB[4 * jq + 3] = fmaf(hb, w.w, pB[4 * jq + 3]);
        }
    }
#pragma unroll
    for (int m = 1; m < 8; m <<= 1) {
#pragma unroll
        for (int j = 0; j < 24; j++) {
            pA[j] += __shfl_xor(pA[j], m, 8);
            pB[j] += __shfl_xor(pB[j], m, 8);
        }
    }
    if (nodeA < N) {
        float* orow = out + (size_t)nodeA * 24 + jg * 3;
        orow[0] = pA[jg * 3 + 0];
        orow[1] = pA[jg * 3 + 1];
        orow[2] = pA[jg * 3 + 2];
    }
    if (nodeB < N) {
        float* orow = out + (size_t)nodeB * 24 + jg * 3;
        orow[0] = pB[jg * 3 + 0];
        orow[1] = pB[jg * 3 + 1];
        orow[2] = pB[jg * 3 + 2];
    }
}

// ======================= launch ==========================================
extern "C" void kernel_launch(void* const* d_in, const int* in_sizes, int n_in,
                              void* d_out, int out_size, void* d_ws, size_t ws_size,
                              hipStream_t stream) {
    const float* x  = (const float*)d_in[0];
    const int*   ei = (const int*)d_in[1];
    const float* W1 = (const float*)d_in[2]; const float* b1 = (const float*)d_in[3];
    const float* W2 = (const float*)d_in[4]; const float* b2 = (const float*)d_in[5];
    const float* W3 = (const float*)d_in[6]; const float* b3 = (const float*)d_in[7];
    const float* W4 = (const float*)d_in[8]; const float* b4 = (const float*)d_in[9];
    const int* row = ei;
    const int* col = ei + NE;
    float* out = (float*)d_out;

    // workspace layout (floats)
    float* A      = (float*)d_ws;                  // N x 128
    float* B      = A + (size_t)NN * 128;          // N x 128
    float* dinv   = B + (size_t)NN * 128;          // N
    int*   rowptr = (int*)(dinv + NN);             // N
    int*   rowend = rowptr + NN;                   // N
    int*   csr_row= rowend + NN;                   // NB_BKT * CSRCAP = 2.5M
    int*   bcur   = csr_row + (size_t)NB_BKT * CSRCAP;   // NB_BKT
    // packed u32 (r<<7 | c&127), bucket-strided cap BCAP; aliases A (dead pre-L1)
    unsigned int* packed = (unsigned int*)A;       // NB_BKT * BCAP = 2.4M < N*128

    const int BS = 256;
    const int NCH = cdiv(NE, CHUNK);    // 196

    // ---- padx + bcur init ----
    padx_kernel<<<cdiv((long long)NN * 32, BS), BS, 0, stream>>>(x, B, bcur, NN);
    // ---- fixed-cap bucketed CSR build (2 dispatches) ----
    partition_kernel<<<NCH, 256, 0, stream>>>(row, col, bcur, packed, NE);
    bucket_nodes_place<<<NB_BKT, 256, 0, stream>>>(packed, bcur, rowptr, rowend, dinv, csr_row, NN);

    // ---- L1: fused gather(x32)+gemm 21->32 +b relu : B -> A (stride 32) ----
    gather_gemm<8, 21, 32, 4, 32><<<cdiv(NN, 64), 512, 0, stream>>>(
        (const float4*)B, rowptr, rowend, csr_row, dinv, W1, b1, A, NN);
    // ---- L2: fused gather(h1)+gemm 32->64 +b relu : A -> B (stride 64) ----
    gather_gemm<8, 32, 64, 8, 64><<<cdiv(NN, 64), 512, 0, stream>>>(
        (const float4*)A, rowptr, rowend, csr_row, dinv, W2, b2, B, NN);
    // ---- L3 gather: B -> A (stride 64) ----
    {
        dim3 blk(16, 16);
        gather4_kernel<16, false, false><<<cdiv(NN, 16), blk, 0, stream>>>(
            (const float4*)B, rowptr, rowend, csr_row, dinv, nullptr, A, NN);
    }
    // ---- fused L3+L4 GEMM: A -> B (h4, stride 24) ----
    gemm_l3l4<<<cdiv(NN, 64), 256, 0, stream>>>(A, W3, b3, W4, B, NN);
    // ---- L4 gather + b4: B -> out (stride 21); 96 B/edge rows ----
    {
        dim3 blk(6, 42);
        gather4_kernel<6, true, true><<<cdiv(NN, 42), blk, 0, stream>>>(
            (const float4*)B, rowptr, rowend, csr_row, dinv, b4, out, NN);
    }
}